// Round 16
// baseline (108.049 us; speedup 1.0000x reference)
//
#include <hip/hip_runtime.h>
#include <hip/hip_bf16.h>
#include <cstdint>

typedef __bf16 bf16x8 __attribute__((ext_vector_type(8)));
typedef float f32x4 __attribute__((ext_vector_type(4)));
typedef float f32x16 __attribute__((ext_vector_type(16)));

static constexpr int S = 4096;
static constexpr int D = 768;
static constexpr int DK = 64;

__device__ __forceinline__ unsigned short f2bf(float f) {
  unsigned u = __float_as_uint(f);
  u = (u + 0x7fffu + ((u >> 16) & 1u)) >> 16;
  return (unsigned short)u;
}

// ---------------- fp32 -> bf16 conversion (all 5 tensors, one launch) ------
__global__ __launch_bounds__(256) void cvt5_kernel(
    const float* __restrict__ x, const float* __restrict__ wq,
    const float* __restrict__ wk, const float* __restrict__ wv,
    const float* __restrict__ wo,
    unsigned short* __restrict__ xb, unsigned short* __restrict__ wqb,
    unsigned short* __restrict__ wkb, unsigned short* __restrict__ wvb,
    unsigned short* __restrict__ wob) {
  int i = blockIdx.x * blockDim.x + threadIdx.x;
  constexpr int NX4 = (S * D) / 4;   // 786432
  constexpr int NW4 = (D * D) / 4;   // 147456
  const float* src;
  unsigned short* dst;
  int off;
  if (i < NX4)               { src = x;  dst = xb;  off = i; }
  else if (i < NX4 + NW4)    { src = wq; dst = wqb; off = i - NX4; }
  else if (i < NX4 + 2*NW4)  { src = wk; dst = wkb; off = i - NX4 - NW4; }
  else if (i < NX4 + 3*NW4)  { src = wv; dst = wvb; off = i - NX4 - 2*NW4; }
  else                       { src = wo; dst = wob; off = i - NX4 - 3*NW4; }
  float4 v = reinterpret_cast<const float4*>(src)[off];
  ushort4 o;
  o.x = f2bf(v.x); o.y = f2bf(v.y); o.z = f2bf(v.z); o.w = f2bf(v.w);
  reinterpret_cast<ushort4*>(dst)[off] = o;
}

// ---------------- RoPE cos/sin table: tab[s][i] = (cos, sin) ----------------
__global__ __launch_bounds__(256) void ropetab_kernel(float2* __restrict__ tab) {
  int idx = blockIdx.x * blockDim.x + threadIdx.x;  // s*32 + i, exact grid
  int s = idx >> 5, i = idx & 31;
  float freq = expf(-(float)(2 * i) * (9.210340371976184f / 64.0f));
  float si, c;
  sincosf((float)s * freq, &si, &c);
  tab[idx] = make_float2(c, si);
}

// ---------------- fused QKV GEMM + RoPE (512 threads, dbuf pipeline) -------
// Unchanged from r14 (passing). stage dest is wave-uniform base + lane*16.
__global__ __launch_bounds__(512) void qkv_gemm_kernel(
    const unsigned short* __restrict__ xb,
    const unsigned short* __restrict__ Wall,
    const float2* __restrict__ tab,
    unsigned short* __restrict__ Qh,
    unsigned short* __restrict__ Kf,
    unsigned short* __restrict__ Vf) {
  __shared__ alignas(16) unsigned short At[2][128 * 64];
  __shared__ alignas(16) unsigned short Bt[2][128 * 64];

  const int t = threadIdx.x;
  const int lane = t & 63;
  const int lr = lane & 15;
  const int hi = lane >> 4;
  const int wave = t >> 6;              // 0..7
  const int wr = wave >> 1, wc = wave & 1;
  const int row0 = blockIdx.x * 128;
  const int n0 = blockIdx.y * 128;
  const int sx = lr & 7;                // read-side XOR term

  f32x4 acc[2][4] = {};

  auto stage = [&](int buf, int k0) {
#pragma unroll
    for (int j = 0; j < 2; ++j) {
      const int ci = wave * 128 + j * 64 + lane;  // lane-linear: lds = ci*16B
      const int row = ci >> 3;                    // 0..127
      const int c16 = ci & 7;                     // dest chunk col
      const int csrc = (c16 ^ (row & 7)) * 8;     // inverse-swizzled source col
      __builtin_amdgcn_global_load_lds(
          (const __attribute__((address_space(1))) void*)(
              xb + (size_t)(row0 + row) * 768 + k0 + csrc),
          (__attribute__((address_space(3))) void*)(&At[buf][row * 64 + c16 * 8]),
          16, 0, 0);
      __builtin_amdgcn_global_load_lds(
          (const __attribute__((address_space(1))) void*)(
              Wall + (size_t)(n0 + row) * 768 + k0 + csrc),
          (__attribute__((address_space(3))) void*)(&Bt[buf][row * 64 + c16 * 8]),
          16, 0, 0);
    }
  };

  stage(0, 0);
  __syncthreads();

#pragma unroll
  for (int ts = 0; ts < 12; ++ts) {
    const int cur = ts & 1;
    if (ts + 1 < 12) stage(cur ^ 1, (ts + 1) * 64);  // issue-early (overlaps MFMA)
#pragma unroll
    for (int kk = 0; kk < 2; ++kk) {
      const int csw = ((kk * 4 + hi) ^ sx) * 8;  // swizzled read col (elements)
      bf16x8 a[2], b[4];
#pragma unroll
      for (int rf = 0; rf < 2; ++rf)
        a[rf] = *reinterpret_cast<const bf16x8*>(
            &At[cur][(wr * 32 + rf * 16 + lr) * 64 + csw]);
#pragma unroll
      for (int nf = 0; nf < 4; ++nf)
        b[nf] = *reinterpret_cast<const bf16x8*>(
            &Bt[cur][(wc * 64 + nf * 16 + lr) * 64 + csw]);
#pragma unroll
      for (int rf = 0; rf < 2; ++rf)
#pragma unroll
        for (int nf = 0; nf < 4; ++nf)
          acc[rf][nf] = __builtin_amdgcn_mfma_f32_16x16x32_bf16(a[rf], b[nf], acc[rf][nf], 0, 0, 0);
    }
    __syncthreads();  // one barrier/step
  }

  const int z = n0 / 768;  // 0=Q, 1=K, 2=V (block-uniform; 128 | 768)

  if (z < 2) {
#pragma unroll
    for (int nf = 0; nf < 4; ++nf) {
      const int c = n0 - z * 768 + wc * 64 + nf * 16 + lr;  // 0..767
      const int hh = c >> 6;
      const int dk = c & 63;
      const int ii = dk >> 1;
#pragma unroll
      for (int rf = 0; rf < 2; ++rf) {
        const int jrow = row0 + wr * 32 + rf * 16 + hi * 4;
#pragma unroll
        for (int j = 0; j < 4; ++j) {
          float v = acc[rf][nf][j];
          const int s = jrow + j;
          float pv = __shfl_xor(v, 1);  // partner column (even<->odd)
          float2 cs = tab[(size_t)s * 32 + ii];
          v = (dk & 1) ? (pv * cs.y + v * cs.x) : (v * cs.x - pv * cs.y);
          if (z == 0) {
            // scale = 1/sqrt(64) * log2(e): scores land in log2 units
            Qh[((size_t)hh * S + s) * DK + dk] = f2bf(v * 0.18033688f);
          } else {
            const size_t koff = ((size_t)hh * 128 + (s >> 5)) * 2048 +
                                (size_t)(dk >> 4) * 512 + ((dk >> 3) & 1) * 256 +
                                (s & 31) * 8 + (dk & 7);
            Kf[koff] = f2bf(v);
          }
        }
      }
    }
  } else {
#pragma unroll
    for (int nf = 0; nf < 4; ++nf) {
      const int c = n0 - 1536 + wc * 64 + nf * 16 + lr;
      const int hh = c >> 6;
      const int dv = c & 63;
#pragma unroll
      for (int rf = 0; rf < 2; ++rf) {
        const int jrow = row0 + wr * 32 + rf * 16 + hi * 4;
#pragma unroll
        for (int j = 0; j < 4; ++j) {
          const int s = jrow + j;
          const size_t voff = ((size_t)hh * 256 + (s >> 4)) * 1024 +
                              (size_t)(dv >> 5) * 512 + (dv & 31) * 16 +
                              ((s >> 3) & 1) * 8 + (s & 7);
          Vf[voff] = f2bf(acc[rf][nf][j]);
        }
      }
    }
  }
}

// ---------------- flash attention (causal), persistent 4/CU blocks --------
// Grid (8, 128) = 1024 blocks = exactly the 4-blocks/CU VGPR-cap residency.
// Class c (XCD under id%8) owns 192 (h,qt) items (1.5 heads, L2-resident),
// ranked heavy-first by the verified r14 mapping. Block j runs item rank j
// (pass 0) and rank 255-j (pass 1, valid for j>=64): paired cost ~constant.
// Fixed-max softmax, exp2, T12 pack, T5 setprio around MFMA clusters,
// lsum folded to 4 regs (same math, -12 VGPR).
__global__ __launch_bounds__(256) void attn_kernel(
    const unsigned short* __restrict__ Qh,
    const unsigned short* __restrict__ Kf,
    const unsigned short* __restrict__ Vf,
    unsigned short* __restrict__ AO) {
  const int c = blockIdx.x;           // XCD class
  const int j = blockIdx.y;           // heavy-first rank within class
  const int wave = threadIdx.x >> 6;
  const int lane = threadIdx.x & 63;
  const int lq = lane & 31;
  const int hi2 = lane >> 5;
  const int m3 = 3 * (c >> 1);

  __shared__ float llds[4][32];
  __shared__ float obuf[4][64][17];  // stride 17: conflict-free, 17.4 KB

#pragma unroll 1
  for (int pass = 0; pass < 2; ++pass) {
    const int i = (pass == 0) ? j : 255 - j;
    if (i < 192) {
      const int g = i / 3, r = i - 3 * g;
      int h, qt;
      if ((c & 1) == 0) {  // class 2m: head m3 full + head m3+1 odd qts
        if (r == 0)      { h = m3;     qt = 127 - 2 * g; }
        else if (r == 1) { h = m3 + 1; qt = 127 - 2 * g; }
        else             { h = m3;     qt = 126 - 2 * g; }
      } else {             // class 2m+1: head m3+2 full + head m3+1 even qts
        if (r == 0)      { h = m3 + 2; qt = 127 - 2 * g; }
        else if (r == 1) { h = m3 + 2; qt = 126 - 2 * g; }
        else             { h = m3 + 1; qt = 126 - 2 * g; }
      }

      const int q0w = qt * 32;
      const int qg = q0w + lq;

      const unsigned short* Qp = Qh + ((size_t)h * S + qg) * DK + hi2 * 8;
      const unsigned short* Kfp = Kf + (size_t)h * (S * DK) + hi2 * 256 + lq * 8;
      const unsigned short* Vfp = Vf + (size_t)h * (S * DK) + lq * 16 + hi2 * 8;

      bf16x8 qf[4];
#pragma unroll
      for (int ks = 0; ks < 4; ++ks)
        qf[ks] = *reinterpret_cast<const bf16x8*>(Qp + ks * 16);

      f32x16 acc0 = {}, acc1 = {};
      float lsum[4] = {0.f, 0.f, 0.f, 0.f};

      const int kvmax = ((q0w + 31) >> 6) << 6;  // last tile start
      const int kvfirst = 64 * wave;

      // preload this wave's first K tile
      bf16x8 ka[2][4];
      if (kvfirst <= kvmax) {
        const unsigned short* K0 = Kfp + ((size_t)(kvfirst >> 5)) * 2048;
#pragma unroll
        for (int tt = 0; tt < 2; ++tt)
#pragma unroll
          for (int ks = 0; ks < 4; ++ks)
            ka[tt][ks] = *reinterpret_cast<const bf16x8*>(K0 + (size_t)tt * 2048 + ks * 512);
      }

      for (int kv0 = kvfirst; kv0 <= kvmax; kv0 += 256) {
        // V B-frags: issue early, consumed after softmax
        bf16x8 vb[2][4];
#pragma unroll
        for (int dvh = 0; dvh < 2; ++dvh)
#pragma unroll
          for (int ks = 0; ks < 4; ++ks)
            vb[dvh][ks] = *reinterpret_cast<const bf16x8*>(
                Vfp + ((size_t)(kv0 >> 4) + ks) * 1024 + dvh * 512);

        // S^T (log2 units): lane holds q=lq, kv = kv0 + 32t + crow(r,hi2)
        f32x16 s0 = {}, s1 = {};
        __builtin_amdgcn_s_setprio(1);
#pragma unroll
        for (int ks = 0; ks < 4; ++ks) {
          s0 = __builtin_amdgcn_mfma_f32_32x32x16_bf16(ka[0][ks], qf[ks], s0, 0, 0, 0);
          s1 = __builtin_amdgcn_mfma_f32_32x32x16_bf16(ka[1][ks], qf[ks], s1, 0, 0, 0);
        }
        __builtin_amdgcn_s_setprio(0);

        // prefetch this wave's next K tile
        if ((kv0 + 256) <= kvmax) {
          const unsigned short* Kn = Kfp + ((size_t)((kv0 + 256) >> 5)) * 2048;
#pragma unroll
          for (int tt = 0; tt < 2; ++tt)
#pragma unroll
            for (int ks = 0; ks < 4; ++ks)
              ka[tt][ks] = *reinterpret_cast<const bf16x8*>(Kn + (size_t)tt * 2048 + ks * 512);
        }

        // causal mask (diag tiles only; wave-uniform branch)
        if ((kv0 + 63) > q0w) {
#pragma unroll
          for (int rr = 0; rr < 16; ++rr) {
            const int kvr = kv0 + (rr & 3) + 8 * (rr >> 2) + 4 * hi2;
            if (kvr > qg) s0[rr] = -1e30f;
            if (kvr + 32 > qg) s1[rr] = -1e30f;
          }
        }

        // P = exp2(s) in place; accumulate row sum into 4 regs
#pragma unroll
        for (int rr = 0; rr < 16; ++rr) {
          float e0, e1;
          asm("v_exp_f32 %0, %1" : "=v"(e0) : "v"(s0[rr]));
          asm("v_exp_f32 %0, %1" : "=v"(e1) : "v"(s1[rr]));
          s0[rr] = e0;
          s1[rr] = e1;
          lsum[rr & 3] += e0 + e1;
        }

        // P->A-frags (T12): cvt_pk + permlane32_swap
        bf16x8 pa[4];
#pragma unroll
        for (int ks = 0; ks < 4; ++ks) {
          const int a4 = 8 * (ks & 1);
          unsigned X01, X23, Y01, Y23;
          if (ks < 2) {
            asm("v_cvt_pk_bf16_f32 %0, %1, %2" : "=v"(X01) : "v"(s0[a4 + 0]), "v"(s0[a4 + 1]));
            asm("v_cvt_pk_bf16_f32 %0, %1, %2" : "=v"(X23) : "v"(s0[a4 + 2]), "v"(s0[a4 + 3]));
            asm("v_cvt_pk_bf16_f32 %0, %1, %2" : "=v"(Y01) : "v"(s0[a4 + 4]), "v"(s0[a4 + 5]));
            asm("v_cvt_pk_bf16_f32 %0, %1, %2" : "=v"(Y23) : "v"(s0[a4 + 6]), "v"(s0[a4 + 7]));
          } else {
            asm("v_cvt_pk_bf16_f32 %0, %1, %2" : "=v"(X01) : "v"(s1[a4 + 0]), "v"(s1[a4 + 1]));
            asm("v_cvt_pk_bf16_f32 %0, %1, %2" : "=v"(X23) : "v"(s1[a4 + 2]), "v"(s1[a4 + 3]));
            asm("v_cvt_pk_bf16_f32 %0, %1, %2" : "=v"(Y01) : "v"(s1[a4 + 4]), "v"(s1[a4 + 5]));
            asm("v_cvt_pk_bf16_f32 %0, %1, %2" : "=v"(Y23) : "v"(s1[a4 + 6]), "v"(s1[a4 + 7]));
          }
          asm volatile("v_permlane32_swap_b32 %0, %1" : "+v"(X01), "+v"(Y01));
          asm volatile("v_permlane32_swap_b32 %0, %1" : "+v"(X23), "+v"(Y23));
          union { unsigned u[4]; bf16x8 v; } P;
          P.u[0] = X01; P.u[1] = X23; P.u[2] = Y01; P.u[3] = Y23;
          pa[ks] = P.v;
        }

        // O^acc += P @ V
        __builtin_amdgcn_s_setprio(1);
#pragma unroll
        for (int ks = 0; ks < 4; ++ks) {
          acc0 = __builtin_amdgcn_mfma_f32_32x32x16_bf16(pa[ks], vb[0][ks], acc0, 0, 0, 0);
          acc1 = __builtin_amdgcn_mfma_f32_32x32x16_bf16(pa[ks], vb[1][ks], acc1, 0, 0, 0);
        }
        __builtin_amdgcn_s_setprio(0);
      }

      // final l for this wave
      const float lw = (lsum[0] + lsum[1]) + (lsum[2] + lsum[3]);
      const float l_ = lw + __shfl_xor(lw, 32);

      // ---- combine across the 4 kv-split waves, TWO passes ----
      if (hi2 == 0) llds[wave][lq] = l_;

      // pass 1: acc0
#pragma unroll
      for (int rr = 0; rr < 16; ++rr) obuf[wave][lane][rr] = acc0[rr];
      __syncthreads();

      const float Ltot = llds[0][lq] + llds[1][lq] + llds[2][lq] + llds[3][lq];
      const float linv = 1.0f / Ltot;

      float v0[4];
#pragma unroll
      for (int rr = 0; rr < 4; ++rr) {
        const int rq = wave * 4 + rr;
        v0[rr] = obuf[0][lane][rq] + obuf[1][lane][rq] + obuf[2][lane][rq] + obuf[3][lane][rq];
      }
      __syncthreads();

      // pass 2: acc1
#pragma unroll
      for (int rr = 0; rr < 16; ++rr) obuf[wave][lane][rr] = acc1[rr];
      __syncthreads();

#pragma unroll
      for (int rr = 0; rr < 4; ++rr) {
        const int rq = wave * 4 + rr;
        const float v1 = obuf[0][lane][rq] + obuf[1][lane][rq] + obuf[2][lane][rq] + obuf[3][lane][rq];
        const int row = (rq & 3) + 8 * (rq >> 2) + 4 * hi2;
        const float li = __shfl(linv, row);
        const size_t s = q0w + row;
        AO[s * D + h * DK + lq]      = f2bf(v0[rr] * li);
        AO[s * D + h * DK + 32 + lq] = f2bf(v1 * li);
      }
      __syncthreads();  // obuf/llds safe for next pass
    }
  }
}

// ---------------- output projection (dbuf single-barrier GEMM) -------------
__global__ __launch_bounds__(256) void oproj_kernel(
    const unsigned short* __restrict__ AO,
    const unsigned short* __restrict__ Wob,
    float* __restrict__ out) {
  __shared__ alignas(16) unsigned short At[2][128 * 64];
  __shared__ alignas(16) unsigned short Bt[2][128 * 64];

  const int t = threadIdx.x;
  const int lane = t & 63;
  const int lr = lane & 15;
  const int hi = lane >> 4;
  const int wave = t >> 6;
  const int wr = wave >> 1, wc = wave & 1;
  const int row0 = blockIdx.x * 128;
  const int n0 = blockIdx.y * 128;

  const int trow = t >> 3;
  const int tc8  = (t & 7) * 8;
  const int tsw8 = (((t & 7) ^ (trow & 7)) * 8);
  const int sx = lr & 7;

  f32x4 acc[4][4] = {};

  auto stage = [&](int buf, int k0) {
#pragma unroll
    for (int i = 0; i < 4; ++i) {
      __builtin_amdgcn_global_load_lds(
          (const __attribute__((address_space(1))) void*)(
              AO + (size_t)(row0 + trow + 32 * i) * 768 + k0 + tsw8),
          (__attribute__((address_space(3))) void*)(&At[buf][(trow + 32 * i) * 64 + tc8]),
          16, 0, 0);
      __builtin_amdgcn_global_load_lds(
          (const __attribute__((address_space(1))) void*)(
              Wob + (size_t)(n0 + trow + 32 * i) * 768 + k0 + tsw8),
          (__attribute__((address_space(3))) void*)(&Bt[buf][(trow + 32 * i) * 64 + tc8]),
          16, 0, 0);
    }
  };

  stage(0, 0);
  __syncthreads();

#pragma unroll
  for (int ts = 0; ts < 12; ++ts) {
    const int cur = ts & 1;
    if (ts + 1 < 12) stage(cur ^ 1, (ts + 1) * 64);
#pragma unroll
    for (int kk = 0; kk < 2; ++kk) {
      const int csw = ((kk * 4 + hi) ^ sx) * 8;
      bf16x8 a[4], b[4];
#pragma unroll
      for (int rf = 0; rf < 4; ++rf)
        a[rf] = *reinterpret_cast<const bf16x8*>(
            &At[cur][(wr * 64 + rf * 16 + lr) * 64 + csw]);
#pragma unroll
      for (int nf = 0; nf < 4; ++nf)
        b[nf] = *reinterpret_cast<const bf16x8*>(
            &Bt[cur][(wc * 64 + nf * 16 + lr) * 64 + csw]);
#pragma unroll
      for (int rf = 0; rf < 4; ++rf)
#pragma unroll
        for (int nf = 0; nf < 4; ++nf)
          acc[rf][nf] = __builtin_amdgcn_mfma_f32_16x16x32_bf16(a[rf], b[nf], acc[rf][nf], 0, 0, 0);
    }
    __syncthreads();
  }

#pragma unroll
  for (int rf = 0; rf < 4; ++rf) {
    const int jrow = row0 + wr * 64 + rf * 16 + hi * 4;
#pragma unroll
    for (int nf = 0; nf < 4; ++nf) {
      const int cn = n0 + wc * 64 + nf * 16 + lr;
#pragma unroll
      for (int j = 0; j < 4; ++j)
        out[(size_t)(jrow + j) * D + cn] = acc[rf][nf][j];
    }
  }
}

extern "C" void kernel_launch(void* const* d_in, const int* in_sizes, int n_in,
                              void* d_out, int out_size, void* d_ws, size_t ws_size,
                              hipStream_t stream) {
  const float* x  = (const float*)d_in[0];
  const float* Wq = (const float*)d_in[1];
  const float* Wk = (const float*)d_in[2];
  const float* Wv = (const float*)d_in[3];
  const float* Wo = (const float*)d_in[4];
  float* out = (float*)d_out;

  char* ws = (char*)d_ws;
  unsigned short* xb  = (unsigned short*)(ws + 0);
  unsigned short* Wqb = (unsigned short*)(ws + 6291456);
  unsigned short* Wkb = (unsigned short*)(ws + 7471104);
  unsigned short* Wvb = (unsigned short*)(ws + 8650752);
  unsigned short* Wob = (unsigned short*)(ws + 9830400);
  unsigned short* Qh  = (unsigned short*)(ws + 11010048);  // [H][S][64] row-major
  unsigned short* Kf  = (unsigned short*)(ws + 17301504);  // frag-major K
  unsigned short* Vf  = (unsigned short*)(ws + 23592960);  // frag-major V
  unsigned short* AO  = (unsigned short*)(ws + 29884416);  // [S][D]
  // rope table overlaps the first 1 MB of the AO region: tab is fully
  // consumed by qkv_gemm_kernel before attn_kernel writes AO (stream order).
  float2* tab = (float2*)(ws + 29884416);

  cvt5_kernel<<<5376, 256, 0, stream>>>(x, Wq, Wk, Wv, Wo, xb, Wqb, Wkb, Wvb, Wob);
  ropetab_kernel<<<512, 256, 0, stream>>>(tab);
  // Wqb|Wkb|Wvb are contiguous -> one stacked weight matrix [2304][768]
  qkv_gemm_kernel<<<dim3(32, 18), 512, 0, stream>>>(xb, Wqb, tab, Qh, Kf, Vf);
  // persistent 4/CU blocks, XCD-partitioned, heavy-first paired ranks
  attn_kernel<<<dim3(8, 128), 256, 0, stream>>>(Qh, Kf, Vf, AO);
  oproj_kernel<<<dim3(32, 6), 256, 0, stream>>>(AO, Wob, out);
}

// Round 17
// 102.082 us; speedup vs baseline: 1.0584x; 1.0584x over previous
//
#include <hip/hip_runtime.h>
#include <hip/hip_bf16.h>
#include <cstdint>

typedef __bf16 bf16x8 __attribute__((ext_vector_type(8)));
typedef float f32x4 __attribute__((ext_vector_type(4)));
typedef float f32x16 __attribute__((ext_vector_type(16)));

static constexpr int S = 4096;
static constexpr int D = 768;
static constexpr int DK = 64;

__device__ __forceinline__ unsigned short f2bf(float f) {
  unsigned u = __float_as_uint(f);
  u = (u + 0x7fffu + ((u >> 16) & 1u)) >> 16;
  return (unsigned short)u;
}

// ------- fp32 -> bf16 conversion (5 tensors) + RoPE table, one launch ------
__global__ __launch_bounds__(256) void cvt5_kernel(
    const float* __restrict__ x, const float* __restrict__ wq,
    const float* __restrict__ wk, const float* __restrict__ wv,
    const float* __restrict__ wo,
    unsigned short* __restrict__ xb, unsigned short* __restrict__ wqb,
    unsigned short* __restrict__ wkb, unsigned short* __restrict__ wvb,
    unsigned short* __restrict__ wob, float2* __restrict__ tab) {
  int i = blockIdx.x * blockDim.x + threadIdx.x;
  constexpr int NX4 = (S * D) / 4;   // 786432
  constexpr int NW4 = (D * D) / 4;   // 147456
  constexpr int NC = NX4 + 4 * NW4;  // 1376256 cvt items
  if (i < NC) {
    const float* src;
    unsigned short* dst;
    int off;
    if (i < NX4)               { src = x;  dst = xb;  off = i; }
    else if (i < NX4 + NW4)    { src = wq; dst = wqb; off = i - NX4; }
    else if (i < NX4 + 2*NW4)  { src = wk; dst = wkb; off = i - NX4 - NW4; }
    else if (i < NX4 + 3*NW4)  { src = wv; dst = wvb; off = i - NX4 - 2*NW4; }
    else                       { src = wo; dst = wob; off = i - NX4 - 3*NW4; }
    float4 v = reinterpret_cast<const float4*>(src)[off];
    ushort4 o;
    o.x = f2bf(v.x); o.y = f2bf(v.y); o.z = f2bf(v.z); o.w = f2bf(v.w);
    reinterpret_cast<ushort4*>(dst)[off] = o;
  } else {
    int idx = i - NC;          // 0 .. S*32-1
    if (idx < S * 32) {
      int s = idx >> 5, ii = idx & 31;
      float freq = expf(-(float)(2 * ii) * (9.210340371976184f / 64.0f));
      float si, c;
      sincosf((float)s * freq, &si, &c);
      tab[idx] = make_float2(c, si);
    }
  }
}

// ---------------- fused QKV GEMM + RoPE (512 threads, dbuf pipeline) -------
// Unchanged (passing, ~33us). stage dest is wave-uniform base + lane*16.
__global__ __launch_bounds__(512) void qkv_gemm_kernel(
    const unsigned short* __restrict__ xb,
    const unsigned short* __restrict__ Wall,
    const float2* __restrict__ tab,
    unsigned short* __restrict__ Qh,
    unsigned short* __restrict__ Kf,
    unsigned short* __restrict__ Vf) {
  __shared__ alignas(16) unsigned short At[2][128 * 64];
  __shared__ alignas(16) unsigned short Bt[2][128 * 64];

  const int t = threadIdx.x;
  const int lane = t & 63;
  const int lr = lane & 15;
  const int hi = lane >> 4;
  const int wave = t >> 6;              // 0..7
  const int wr = wave >> 1, wc = wave & 1;
  const int row0 = blockIdx.x * 128;
  const int n0 = blockIdx.y * 128;
  const int sx = lr & 7;                // read-side XOR term

  f32x4 acc[2][4] = {};

  auto stage = [&](int buf, int k0) {
#pragma unroll
    for (int j = 0; j < 2; ++j) {
      const int ci = wave * 128 + j * 64 + lane;  // lane-linear: lds = ci*16B
      const int row = ci >> 3;                    // 0..127
      const int c16 = ci & 7;                     // dest chunk col
      const int csrc = (c16 ^ (row & 7)) * 8;     // inverse-swizzled source col
      __builtin_amdgcn_global_load_lds(
          (const __attribute__((address_space(1))) void*)(
              xb + (size_t)(row0 + row) * 768 + k0 + csrc),
          (__attribute__((address_space(3))) void*)(&At[buf][row * 64 + c16 * 8]),
          16, 0, 0);
      __builtin_amdgcn_global_load_lds(
          (const __attribute__((address_space(1))) void*)(
              Wall + (size_t)(n0 + row) * 768 + k0 + csrc),
          (__attribute__((address_space(3))) void*)(&Bt[buf][row * 64 + c16 * 8]),
          16, 0, 0);
    }
  };

  stage(0, 0);
  __syncthreads();

#pragma unroll
  for (int ts = 0; ts < 12; ++ts) {
    const int cur = ts & 1;
    if (ts + 1 < 12) stage(cur ^ 1, (ts + 1) * 64);  // issue-early (overlaps MFMA)
#pragma unroll
    for (int kk = 0; kk < 2; ++kk) {
      const int csw = ((kk * 4 + hi) ^ sx) * 8;  // swizzled read col (elements)
      bf16x8 a[2], b[4];
#pragma unroll
      for (int rf = 0; rf < 2; ++rf)
        a[rf] = *reinterpret_cast<const bf16x8*>(
            &At[cur][(wr * 32 + rf * 16 + lr) * 64 + csw]);
#pragma unroll
      for (int nf = 0; nf < 4; ++nf)
        b[nf] = *reinterpret_cast<const bf16x8*>(
            &Bt[cur][(wc * 64 + nf * 16 + lr) * 64 + csw]);
#pragma unroll
      for (int rf = 0; rf < 2; ++rf)
#pragma unroll
        for (int nf = 0; nf < 4; ++nf)
          acc[rf][nf] = __builtin_amdgcn_mfma_f32_16x16x32_bf16(a[rf], b[nf], acc[rf][nf], 0, 0, 0);
    }
    __syncthreads();  // one barrier/step
  }

  const int z = n0 / 768;  // 0=Q, 1=K, 2=V (block-uniform; 128 | 768)

  if (z < 2) {
#pragma unroll
    for (int nf = 0; nf < 4; ++nf) {
      const int c = n0 - z * 768 + wc * 64 + nf * 16 + lr;  // 0..767
      const int hh = c >> 6;
      const int dk = c & 63;
      const int ii = dk >> 1;
#pragma unroll
      for (int rf = 0; rf < 2; ++rf) {
        const int jrow = row0 + wr * 32 + rf * 16 + hi * 4;
#pragma unroll
        for (int j = 0; j < 4; ++j) {
          float v = acc[rf][nf][j];
          const int s = jrow + j;
          float pv = __shfl_xor(v, 1);  // partner column (even<->odd)
          float2 cs = tab[(size_t)s * 32 + ii];
          v = (dk & 1) ? (pv * cs.y + v * cs.x) : (v * cs.x - pv * cs.y);
          if (z == 0) {
            // scale = 1/sqrt(64) * log2(e): scores land in log2 units
            Qh[((size_t)hh * S + s) * DK + dk] = f2bf(v * 0.18033688f);
          } else {
            const size_t koff = ((size_t)hh * 128 + (s >> 5)) * 2048 +
                                (size_t)(dk >> 4) * 512 + ((dk >> 3) & 1) * 256 +
                                (s & 31) * 8 + (dk & 7);
            Kf[koff] = f2bf(v);
          }
        }
      }
    }
  } else {
#pragma unroll
    for (int nf = 0; nf < 4; ++nf) {
      const int c = n0 - 1536 + wc * 64 + nf * 16 + lr;
      const int hh = c >> 6;
      const int dv = c & 63;
#pragma unroll
      for (int rf = 0; rf < 2; ++rf) {
        const int jrow = row0 + wr * 32 + rf * 16 + hi * 4;
#pragma unroll
        for (int j = 0; j < 4; ++j) {
          const int s = jrow + j;
          const size_t voff = ((size_t)hh * 256 + (s >> 4)) * 1024 +
                              (size_t)(dv >> 5) * 512 + (dv & 31) * 16 +
                              ((s >> 3) & 1) * 8 + (s & 7);
          Vf[voff] = f2bf(acc[rf][nf][j]);
        }
      }
    }
  }
}

// ---------------- flash attention (causal), 4-way KV-split ----------------
// EXACT r14 structure (measured 48us): grid (8,192), blockIdx.y = dispatch
// time axis, balanced heavy-first class mapping, independent blocks, no
// setprio, no pass loop. Only r15 piece kept: lsum[4] fold (same math,
// -12 VGPR). Fixed-max softmax, exp2, T12 pack, fragment-major Kf/Vf.
__global__ __launch_bounds__(256) void attn_kernel(
    const unsigned short* __restrict__ Qh,
    const unsigned short* __restrict__ Kf,
    const unsigned short* __restrict__ Vf,
    unsigned short* __restrict__ AO) {
  const int c = blockIdx.x;           // XCD class under id%8 round-robin
  const int sslot = blockIdx.y;       // dispatch-time slot 0..191
  const int m3 = 3 * (c >> 1);
  const int g = sslot / 3, r = sslot - 3 * g;
  int h, qt;
  if ((c & 1) == 0) {  // class 2m: head m3 full + head m3+1 odd qts
    if (r == 0)      { h = m3;     qt = 127 - 2 * g; }
    else if (r == 1) { h = m3 + 1; qt = 127 - 2 * g; }
    else             { h = m3;     qt = 126 - 2 * g; }
  } else {             // class 2m+1: head m3+2 full + head m3+1 even qts
    if (r == 0)      { h = m3 + 2; qt = 127 - 2 * g; }
    else if (r == 1) { h = m3 + 2; qt = 126 - 2 * g; }
    else             { h = m3 + 1; qt = 126 - 2 * g; }
  }

  const int wave = threadIdx.x >> 6;
  const int lane = threadIdx.x & 63;
  const int lq = lane & 31;
  const int hi2 = lane >> 5;
  const int q0w = qt * 32;
  const int qg = q0w + lq;

  const unsigned short* Qp = Qh + ((size_t)h * S + qg) * DK + hi2 * 8;
  const unsigned short* Kfp = Kf + (size_t)h * (S * DK) + hi2 * 256 + lq * 8;
  const unsigned short* Vfp = Vf + (size_t)h * (S * DK) + lq * 16 + hi2 * 8;

  bf16x8 qf[4];
#pragma unroll
  for (int ks = 0; ks < 4; ++ks)
    qf[ks] = *reinterpret_cast<const bf16x8*>(Qp + ks * 16);

  f32x16 acc0 = {}, acc1 = {};
  float lsum[4] = {0.f, 0.f, 0.f, 0.f};

  const int kvmax = ((q0w + 31) >> 6) << 6;  // last tile start
  const int kvfirst = 64 * wave;

  // preload this wave's first K tile
  bf16x8 ka[2][4];
  if (kvfirst <= kvmax) {
    const unsigned short* K0 = Kfp + ((size_t)(kvfirst >> 5)) * 2048;
#pragma unroll
    for (int tt = 0; tt < 2; ++tt)
#pragma unroll
      for (int ks = 0; ks < 4; ++ks)
        ka[tt][ks] = *reinterpret_cast<const bf16x8*>(K0 + (size_t)tt * 2048 + ks * 512);
  }

  for (int kv0 = kvfirst; kv0 <= kvmax; kv0 += 256) {
    // V B-frags: issue early, consumed after softmax
    bf16x8 vb[2][4];
#pragma unroll
    for (int dvh = 0; dvh < 2; ++dvh)
#pragma unroll
      for (int ks = 0; ks < 4; ++ks)
        vb[dvh][ks] = *reinterpret_cast<const bf16x8*>(
            Vfp + ((size_t)(kv0 >> 4) + ks) * 1024 + dvh * 512);

    // S^T (log2 units): lane holds q=lq, kv = kv0 + 32t + crow(r,hi2)
    f32x16 s0 = {}, s1 = {};
#pragma unroll
    for (int ks = 0; ks < 4; ++ks) {
      s0 = __builtin_amdgcn_mfma_f32_32x32x16_bf16(ka[0][ks], qf[ks], s0, 0, 0, 0);
      s1 = __builtin_amdgcn_mfma_f32_32x32x16_bf16(ka[1][ks], qf[ks], s1, 0, 0, 0);
    }

    // prefetch this wave's next K tile
    if ((kv0 + 256) <= kvmax) {
      const unsigned short* Kn = Kfp + ((size_t)((kv0 + 256) >> 5)) * 2048;
#pragma unroll
      for (int tt = 0; tt < 2; ++tt)
#pragma unroll
        for (int ks = 0; ks < 4; ++ks)
          ka[tt][ks] = *reinterpret_cast<const bf16x8*>(Kn + (size_t)tt * 2048 + ks * 512);
    }

    // causal mask (diag tiles only; wave-uniform branch)
    if ((kv0 + 63) > q0w) {
#pragma unroll
      for (int rr = 0; rr < 16; ++rr) {
        const int kvr = kv0 + (rr & 3) + 8 * (rr >> 2) + 4 * hi2;
        if (kvr > qg) s0[rr] = -1e30f;
        if (kvr + 32 > qg) s1[rr] = -1e30f;
      }
    }

    // P = exp2(s) in place; accumulate row sum into 4 regs
#pragma unroll
    for (int rr = 0; rr < 16; ++rr) {
      float e0, e1;
      asm("v_exp_f32 %0, %1" : "=v"(e0) : "v"(s0[rr]));
      asm("v_exp_f32 %0, %1" : "=v"(e1) : "v"(s1[rr]));
      s0[rr] = e0;
      s1[rr] = e1;
      lsum[rr & 3] += e0 + e1;
    }

    // P->A-frags (T12): cvt_pk + permlane32_swap
    bf16x8 pa[4];
#pragma unroll
    for (int ks = 0; ks < 4; ++ks) {
      const int a4 = 8 * (ks & 1);
      unsigned X01, X23, Y01, Y23;
      if (ks < 2) {
        asm("v_cvt_pk_bf16_f32 %0, %1, %2" : "=v"(X01) : "v"(s0[a4 + 0]), "v"(s0[a4 + 1]));
        asm("v_cvt_pk_bf16_f32 %0, %1, %2" : "=v"(X23) : "v"(s0[a4 + 2]), "v"(s0[a4 + 3]));
        asm("v_cvt_pk_bf16_f32 %0, %1, %2" : "=v"(Y01) : "v"(s0[a4 + 4]), "v"(s0[a4 + 5]));
        asm("v_cvt_pk_bf16_f32 %0, %1, %2" : "=v"(Y23) : "v"(s0[a4 + 6]), "v"(s0[a4 + 7]));
      } else {
        asm("v_cvt_pk_bf16_f32 %0, %1, %2" : "=v"(X01) : "v"(s1[a4 + 0]), "v"(s1[a4 + 1]));
        asm("v_cvt_pk_bf16_f32 %0, %1, %2" : "=v"(X23) : "v"(s1[a4 + 2]), "v"(s1[a4 + 3]));
        asm("v_cvt_pk_bf16_f32 %0, %1, %2" : "=v"(Y01) : "v"(s1[a4 + 4]), "v"(s1[a4 + 5]));
        asm("v_cvt_pk_bf16_f32 %0, %1, %2" : "=v"(Y23) : "v"(s1[a4 + 6]), "v"(s1[a4 + 7]));
      }
      asm volatile("v_permlane32_swap_b32 %0, %1" : "+v"(X01), "+v"(Y01));
      asm volatile("v_permlane32_swap_b32 %0, %1" : "+v"(X23), "+v"(Y23));
      union { unsigned u[4]; bf16x8 v; } P;
      P.u[0] = X01; P.u[1] = X23; P.u[2] = Y01; P.u[3] = Y23;
      pa[ks] = P.v;
    }

    // O^acc += P @ V
#pragma unroll
    for (int ks = 0; ks < 4; ++ks) {
      acc0 = __builtin_amdgcn_mfma_f32_32x32x16_bf16(pa[ks], vb[0][ks], acc0, 0, 0, 0);
      acc1 = __builtin_amdgcn_mfma_f32_32x32x16_bf16(pa[ks], vb[1][ks], acc1, 0, 0, 0);
    }
  }

  // final l for this wave
  const float lw = (lsum[0] + lsum[1]) + (lsum[2] + lsum[3]);
  const float l_ = lw + __shfl_xor(lw, 32);

  // ---- combine across the 4 kv-split waves, TWO passes (half the LDS) ----
  __shared__ float llds[4][32];
  __shared__ float obuf[4][64][17];  // stride 17: conflict-free, 17.4 KB

  if (hi2 == 0) llds[wave][lq] = l_;

  // pass 1: acc0
#pragma unroll
  for (int rr = 0; rr < 16; ++rr) obuf[wave][lane][rr] = acc0[rr];
  __syncthreads();

  const float Ltot = llds[0][lq] + llds[1][lq] + llds[2][lq] + llds[3][lq];
  const float linv = 1.0f / Ltot;

  float v0[4];
#pragma unroll
  for (int rr = 0; rr < 4; ++rr) {
    const int rq = wave * 4 + rr;
    v0[rr] = obuf[0][lane][rq] + obuf[1][lane][rq] + obuf[2][lane][rq] + obuf[3][lane][rq];
  }
  __syncthreads();

  // pass 2: acc1
#pragma unroll
  for (int rr = 0; rr < 16; ++rr) obuf[wave][lane][rr] = acc1[rr];
  __syncthreads();

#pragma unroll
  for (int rr = 0; rr < 4; ++rr) {
    const int rq = wave * 4 + rr;
    const float v1 = obuf[0][lane][rq] + obuf[1][lane][rq] + obuf[2][lane][rq] + obuf[3][lane][rq];
    const int row = (rq & 3) + 8 * (rq >> 2) + 4 * hi2;
    const float li = __shfl(linv, row);
    const size_t s = q0w + row;
    AO[s * D + h * DK + lq]      = f2bf(v0[rr] * li);
    AO[s * D + h * DK + 32 + lq] = f2bf(v1 * li);
  }
}

// ---------------- output projection (dbuf single-barrier GEMM) -------------
__global__ __launch_bounds__(256) void oproj_kernel(
    const unsigned short* __restrict__ AO,
    const unsigned short* __restrict__ Wob,
    float* __restrict__ out) {
  __shared__ alignas(16) unsigned short At[2][128 * 64];
  __shared__ alignas(16) unsigned short Bt[2][128 * 64];

  const int t = threadIdx.x;
  const int lane = t & 63;
  const int lr = lane & 15;
  const int hi = lane >> 4;
  const int wave = t >> 6;
  const int wr = wave >> 1, wc = wave & 1;
  const int row0 = blockIdx.x * 128;
  const int n0 = blockIdx.y * 128;

  const int trow = t >> 3;
  const int tc8  = (t & 7) * 8;
  const int tsw8 = (((t & 7) ^ (trow & 7)) * 8);
  const int sx = lr & 7;

  f32x4 acc[4][4] = {};

  auto stage = [&](int buf, int k0) {
#pragma unroll
    for (int i = 0; i < 4; ++i) {
      __builtin_amdgcn_global_load_lds(
          (const __attribute__((address_space(1))) void*)(
              AO + (size_t)(row0 + trow + 32 * i) * 768 + k0 + tsw8),
          (__attribute__((address_space(3))) void*)(&At[buf][(trow + 32 * i) * 64 + tc8]),
          16, 0, 0);
      __builtin_amdgcn_global_load_lds(
          (const __attribute__((address_space(1))) void*)(
              Wob + (size_t)(n0 + trow + 32 * i) * 768 + k0 + tsw8),
          (__attribute__((address_space(3))) void*)(&Bt[buf][(trow + 32 * i) * 64 + tc8]),
          16, 0, 0);
    }
  };

  stage(0, 0);
  __syncthreads();

#pragma unroll
  for (int ts = 0; ts < 12; ++ts) {
    const int cur = ts & 1;
    if (ts + 1 < 12) stage(cur ^ 1, (ts + 1) * 64);
#pragma unroll
    for (int kk = 0; kk < 2; ++kk) {
      const int csw = ((kk * 4 + hi) ^ sx) * 8;
      bf16x8 a[4], b[4];
#pragma unroll
      for (int rf = 0; rf < 4; ++rf)
        a[rf] = *reinterpret_cast<const bf16x8*>(
            &At[cur][(wr * 64 + rf * 16 + lr) * 64 + csw]);
#pragma unroll
      for (int nf = 0; nf < 4; ++nf)
        b[nf] = *reinterpret_cast<const bf16x8*>(
            &Bt[cur][(wc * 64 + nf * 16 + lr) * 64 + csw]);
#pragma unroll
      for (int rf = 0; rf < 4; ++rf)
#pragma unroll
        for (int nf = 0; nf < 4; ++nf)
          acc[rf][nf] = __builtin_amdgcn_mfma_f32_16x16x32_bf16(a[rf], b[nf], acc[rf][nf], 0, 0, 0);
    }
    __syncthreads();
  }

#pragma unroll
  for (int rf = 0; rf < 4; ++rf) {
    const int jrow = row0 + wr * 64 + rf * 16 + hi * 4;
#pragma unroll
    for (int nf = 0; nf < 4; ++nf) {
      const int cn = n0 + wc * 64 + nf * 16 + lr;
#pragma unroll
      for (int j = 0; j < 4; ++j)
        out[(size_t)(jrow + j) * D + cn] = acc[rf][nf][j];
    }
  }
}

extern "C" void kernel_launch(void* const* d_in, const int* in_sizes, int n_in,
                              void* d_out, int out_size, void* d_ws, size_t ws_size,
                              hipStream_t stream) {
  const float* x  = (const float*)d_in[0];
  const float* Wq = (const float*)d_in[1];
  const float* Wk = (const float*)d_in[2];
  const float* Wv = (const float*)d_in[3];
  const float* Wo = (const float*)d_in[4];
  float* out = (float*)d_out;

  char* ws = (char*)d_ws;
  unsigned short* xb  = (unsigned short*)(ws + 0);
  unsigned short* Wqb = (unsigned short*)(ws + 6291456);
  unsigned short* Wkb = (unsigned short*)(ws + 7471104);
  unsigned short* Wvb = (unsigned short*)(ws + 8650752);
  unsigned short* Wob = (unsigned short*)(ws + 9830400);
  unsigned short* Qh  = (unsigned short*)(ws + 11010048);  // [H][S][64] row-major
  unsigned short* Kf  = (unsigned short*)(ws + 17301504);  // frag-major K
  unsigned short* Vf  = (unsigned short*)(ws + 23592960);  // frag-major V
  unsigned short* AO  = (unsigned short*)(ws + 29884416);  // [S][D]
  // rope table overlaps the first 1 MB of the AO region: tab is fully
  // consumed by qkv_gemm_kernel before attn_kernel writes AO (stream order).
  float2* tab = (float2*)(ws + 29884416);

  // 1376256 cvt items + 131072 tab items = 1507328 -> 5888 blocks x 256
  cvt5_kernel<<<5888, 256, 0, stream>>>(x, Wq, Wk, Wv, Wo, xb, Wqb, Wkb, Wvb, Wob, tab);
  // Wqb|Wkb|Wvb are contiguous -> one stacked weight matrix [2304][768]
  qkv_gemm_kernel<<<dim3(32, 18), 512, 0, stream>>>(xb, Wqb, tab, Qh, Kf, Vf);
  // XCD-partitioned, balanced heavy-first classes (r14 structure)
  attn_kernel<<<dim3(8, 192), 256, 0, stream>>>(Qh, Kf, Vf, AO);
  oproj_kernel<<<dim3(32, 6), 256, 0, stream>>>(AO, Wob, out);
}

// Round 18
// 98.361 us; speedup vs baseline: 1.0985x; 1.0378x over previous
//
#include <hip/hip_runtime.h>
#include <hip/hip_bf16.h>
#include <cstdint>

typedef __bf16 bf16x8 __attribute__((ext_vector_type(8)));
typedef float f32x4 __attribute__((ext_vector_type(4)));
typedef float f32x16 __attribute__((ext_vector_type(16)));

static constexpr int S = 4096;
static constexpr int D = 768;
static constexpr int DK = 64;

__device__ __forceinline__ unsigned short f2bf(float f) {
  unsigned u = __float_as_uint(f);
  u = (u + 0x7fffu + ((u >> 16) & 1u)) >> 16;
  return (unsigned short)u;
}

// ------- fp32 -> bf16 conversion (5 tensors) + RoPE table, one launch ------
__global__ __launch_bounds__(256) void cvt5_kernel(
    const float* __restrict__ x, const float* __restrict__ wq,
    const float* __restrict__ wk, const float* __restrict__ wv,
    const float* __restrict__ wo,
    unsigned short* __restrict__ xb, unsigned short* __restrict__ wqb,
    unsigned short* __restrict__ wkb, unsigned short* __restrict__ wvb,
    unsigned short* __restrict__ wob, float2* __restrict__ tab) {
  int i = blockIdx.x * blockDim.x + threadIdx.x;
  constexpr int NX4 = (S * D) / 4;   // 786432
  constexpr int NW4 = (D * D) / 4;   // 147456
  constexpr int NC = NX4 + 4 * NW4;  // 1376256 cvt items
  if (i < NC) {
    const float* src;
    unsigned short* dst;
    int off;
    if (i < NX4)               { src = x;  dst = xb;  off = i; }
    else if (i < NX4 + NW4)    { src = wq; dst = wqb; off = i - NX4; }
    else if (i < NX4 + 2*NW4)  { src = wk; dst = wkb; off = i - NX4 - NW4; }
    else if (i < NX4 + 3*NW4)  { src = wv; dst = wvb; off = i - NX4 - 2*NW4; }
    else                       { src = wo; dst = wob; off = i - NX4 - 3*NW4; }
    float4 v = reinterpret_cast<const float4*>(src)[off];
    ushort4 o;
    o.x = f2bf(v.x); o.y = f2bf(v.y); o.z = f2bf(v.z); o.w = f2bf(v.w);
    reinterpret_cast<ushort4*>(dst)[off] = o;
  } else {
    int idx = i - NC;          // 0 .. S*32-1
    if (idx < S * 32) {
      int s = idx >> 5, ii = idx & 31;
      float freq = expf(-(float)(2 * ii) * (9.210340371976184f / 64.0f));
      float si, c;
      sincosf((float)s * freq, &si, &c);
      tab[idx] = make_float2(c, si);
    }
  }
}

// ---------------- fused QKV GEMM + RoPE (512 threads, dbuf pipeline) -------
// Unchanged (passing). stage dest is wave-uniform base + lane*16.
__global__ __launch_bounds__(512) void qkv_gemm_kernel(
    const unsigned short* __restrict__ xb,
    const unsigned short* __restrict__ Wall,
    const float2* __restrict__ tab,
    unsigned short* __restrict__ Qh,
    unsigned short* __restrict__ Kf,
    unsigned short* __restrict__ Vf) {
  __shared__ alignas(16) unsigned short At[2][128 * 64];
  __shared__ alignas(16) unsigned short Bt[2][128 * 64];

  const int t = threadIdx.x;
  const int lane = t & 63;
  const int lr = lane & 15;
  const int hi = lane >> 4;
  const int wave = t >> 6;              // 0..7
  const int wr = wave >> 1, wc = wave & 1;
  const int row0 = blockIdx.x * 128;
  const int n0 = blockIdx.y * 128;
  const int sx = lr & 7;                // read-side XOR term

  f32x4 acc[2][4] = {};

  auto stage = [&](int buf, int k0) {
#pragma unroll
    for (int j = 0; j < 2; ++j) {
      const int ci = wave * 128 + j * 64 + lane;  // lane-linear: lds = ci*16B
      const int row = ci >> 3;                    // 0..127
      const int c16 = ci & 7;                     // dest chunk col
      const int csrc = (c16 ^ (row & 7)) * 8;     // inverse-swizzled source col
      __builtin_amdgcn_global_load_lds(
          (const __attribute__((address_space(1))) void*)(
              xb + (size_t)(row0 + row) * 768 + k0 + csrc),
          (__attribute__((address_space(3))) void*)(&At[buf][row * 64 + c16 * 8]),
          16, 0, 0);
      __builtin_amdgcn_global_load_lds(
          (const __attribute__((address_space(1))) void*)(
              Wall + (size_t)(n0 + row) * 768 + k0 + csrc),
          (__attribute__((address_space(3))) void*)(&Bt[buf][row * 64 + c16 * 8]),
          16, 0, 0);
    }
  };

  stage(0, 0);
  __syncthreads();

#pragma unroll
  for (int ts = 0; ts < 12; ++ts) {
    const int cur = ts & 1;
    if (ts + 1 < 12) stage(cur ^ 1, (ts + 1) * 64);  // issue-early (overlaps MFMA)
#pragma unroll
    for (int kk = 0; kk < 2; ++kk) {
      const int csw = ((kk * 4 + hi) ^ sx) * 8;  // swizzled read col (elements)
      bf16x8 a[2], b[4];
#pragma unroll
      for (int rf = 0; rf < 2; ++rf)
        a[rf] = *reinterpret_cast<const bf16x8*>(
            &At[cur][(wr * 32 + rf * 16 + lr) * 64 + csw]);
#pragma unroll
      for (int nf = 0; nf < 4; ++nf)
        b[nf] = *reinterpret_cast<const bf16x8*>(
            &Bt[cur][(wc * 64 + nf * 16 + lr) * 64 + csw]);
#pragma unroll
      for (int rf = 0; rf < 2; ++rf)
#pragma unroll
        for (int nf = 0; nf < 4; ++nf)
          acc[rf][nf] = __builtin_amdgcn_mfma_f32_16x16x32_bf16(a[rf], b[nf], acc[rf][nf], 0, 0, 0);
    }
    __syncthreads();  // one barrier/step
  }

  const int z = n0 / 768;  // 0=Q, 1=K, 2=V (block-uniform; 128 | 768)

  if (z < 2) {
#pragma unroll
    for (int nf = 0; nf < 4; ++nf) {
      const int c = n0 - z * 768 + wc * 64 + nf * 16 + lr;  // 0..767
      const int hh = c >> 6;
      const int dk = c & 63;
      const int ii = dk >> 1;
#pragma unroll
      for (int rf = 0; rf < 2; ++rf) {
        const int jrow = row0 + wr * 32 + rf * 16 + hi * 4;
#pragma unroll
        for (int j = 0; j < 4; ++j) {
          float v = acc[rf][nf][j];
          const int s = jrow + j;
          float pv = __shfl_xor(v, 1);  // partner column (even<->odd)
          float2 cs = tab[(size_t)s * 32 + ii];
          v = (dk & 1) ? (pv * cs.y + v * cs.x) : (v * cs.x - pv * cs.y);
          if (z == 0) {
            // scale = 1/sqrt(64) * log2(e): scores land in log2 units
            Qh[((size_t)hh * S + s) * DK + dk] = f2bf(v * 0.18033688f);
          } else {
            const size_t koff = ((size_t)hh * 128 + (s >> 5)) * 2048 +
                                (size_t)(dk >> 4) * 512 + ((dk >> 3) & 1) * 256 +
                                (s & 31) * 8 + (dk & 7);
            Kf[koff] = f2bf(v);
          }
        }
      }
    }
  } else {
#pragma unroll
    for (int nf = 0; nf < 4; ++nf) {
      const int c = n0 - 1536 + wc * 64 + nf * 16 + lr;
      const int hh = c >> 6;
      const int dv = c & 63;
#pragma unroll
      for (int rf = 0; rf < 2; ++rf) {
        const int jrow = row0 + wr * 32 + rf * 16 + hi * 4;
#pragma unroll
        for (int j = 0; j < 4; ++j) {
          const int s = jrow + j;
          const size_t voff = ((size_t)hh * 256 + (s >> 4)) * 1024 +
                              (size_t)(dv >> 5) * 512 + (dv & 31) * 16 +
                              ((s >> 3) & 1) * 8 + (s & 7);
          Vf[voff] = f2bf(acc[rf][nf][j]);
        }
      }
    }
  }
}

// ---------------- flash attention (causal), 4-way KV-split ----------------
// EXACT r14 body (measured 48.2us twice): grid (8,192), balanced heavy-first
// class mapping, lsum[16] independent accumulators (the r16 lsum[4] fold
// added a 4-deep dependent add chain: +4-5us). Fixed-max softmax, exp2,
// T12 pack, fragment-major Kf/Vf, two-pass combine.
__global__ __launch_bounds__(256) void attn_kernel(
    const unsigned short* __restrict__ Qh,
    const unsigned short* __restrict__ Kf,
    const unsigned short* __restrict__ Vf,
    unsigned short* __restrict__ AO) {
  const int c = blockIdx.x;           // XCD class under id%8 round-robin
  const int sslot = blockIdx.y;       // dispatch-time slot 0..191
  const int m3 = 3 * (c >> 1);
  const int g = sslot / 3, r = sslot - 3 * g;
  int h, qt;
  if ((c & 1) == 0) {  // class 2m: head m3 full + head m3+1 odd qts
    if (r == 0)      { h = m3;     qt = 127 - 2 * g; }
    else if (r == 1) { h = m3 + 1; qt = 127 - 2 * g; }
    else             { h = m3;     qt = 126 - 2 * g; }
  } else {             // class 2m+1: head m3+2 full + head m3+1 even qts
    if (r == 0)      { h = m3 + 2; qt = 127 - 2 * g; }
    else if (r == 1) { h = m3 + 2; qt = 126 - 2 * g; }
    else             { h = m3 + 1; qt = 126 - 2 * g; }
  }

  const int wave = threadIdx.x >> 6;
  const int lane = threadIdx.x & 63;
  const int lq = lane & 31;
  const int hi2 = lane >> 5;
  const int q0w = qt * 32;
  const int qg = q0w + lq;

  const unsigned short* Qp = Qh + ((size_t)h * S + qg) * DK + hi2 * 8;
  const unsigned short* Kfp = Kf + (size_t)h * (S * DK) + hi2 * 256 + lq * 8;
  const unsigned short* Vfp = Vf + (size_t)h * (S * DK) + lq * 16 + hi2 * 8;

  bf16x8 qf[4];
#pragma unroll
  for (int ks = 0; ks < 4; ++ks)
    qf[ks] = *reinterpret_cast<const bf16x8*>(Qp + ks * 16);

  f32x16 acc0 = {}, acc1 = {};
  float lsum[16];
#pragma unroll
  for (int r2 = 0; r2 < 16; ++r2) lsum[r2] = 0.f;

  const int kvmax = ((q0w + 31) >> 6) << 6;  // last tile start
  const int kvfirst = 64 * wave;

  // preload this wave's first K tile
  bf16x8 ka[2][4];
  if (kvfirst <= kvmax) {
    const unsigned short* K0 = Kfp + ((size_t)(kvfirst >> 5)) * 2048;
#pragma unroll
    for (int tt = 0; tt < 2; ++tt)
#pragma unroll
      for (int ks = 0; ks < 4; ++ks)
        ka[tt][ks] = *reinterpret_cast<const bf16x8*>(K0 + (size_t)tt * 2048 + ks * 512);
  }

  for (int kv0 = kvfirst; kv0 <= kvmax; kv0 += 256) {
    // V B-frags: issue early, consumed after softmax
    bf16x8 vb[2][4];
#pragma unroll
    for (int dvh = 0; dvh < 2; ++dvh)
#pragma unroll
      for (int ks = 0; ks < 4; ++ks)
        vb[dvh][ks] = *reinterpret_cast<const bf16x8*>(
            Vfp + ((size_t)(kv0 >> 4) + ks) * 1024 + dvh * 512);

    // S^T (log2 units): lane holds q=lq, kv = kv0 + 32t + crow(r,hi2)
    f32x16 s0 = {}, s1 = {};
#pragma unroll
    for (int ks = 0; ks < 4; ++ks) {
      s0 = __builtin_amdgcn_mfma_f32_32x32x16_bf16(ka[0][ks], qf[ks], s0, 0, 0, 0);
      s1 = __builtin_amdgcn_mfma_f32_32x32x16_bf16(ka[1][ks], qf[ks], s1, 0, 0, 0);
    }

    // prefetch this wave's next K tile
    if ((kv0 + 256) <= kvmax) {
      const unsigned short* Kn = Kfp + ((size_t)((kv0 + 256) >> 5)) * 2048;
#pragma unroll
      for (int tt = 0; tt < 2; ++tt)
#pragma unroll
        for (int ks = 0; ks < 4; ++ks)
          ka[tt][ks] = *reinterpret_cast<const bf16x8*>(Kn + (size_t)tt * 2048 + ks * 512);
    }

    // causal mask (diag tiles only; wave-uniform branch)
    if ((kv0 + 63) > q0w) {
#pragma unroll
      for (int rr = 0; rr < 16; ++rr) {
        const int kvr = kv0 + (rr & 3) + 8 * (rr >> 2) + 4 * hi2;
        if (kvr > qg) s0[rr] = -1e30f;
        if (kvr + 32 > qg) s1[rr] = -1e30f;
      }
    }

    // P = exp2(s) in place; accumulate row sum (16 independent accumulators)
#pragma unroll
    for (int rr = 0; rr < 16; ++rr) {
      float e0, e1;
      asm("v_exp_f32 %0, %1" : "=v"(e0) : "v"(s0[rr]));
      asm("v_exp_f32 %0, %1" : "=v"(e1) : "v"(s1[rr]));
      s0[rr] = e0;
      s1[rr] = e1;
      lsum[rr] += e0 + e1;
    }

    // P->A-frags (T12): cvt_pk + permlane32_swap
    bf16x8 pa[4];
#pragma unroll
    for (int ks = 0; ks < 4; ++ks) {
      const int a4 = 8 * (ks & 1);
      unsigned X01, X23, Y01, Y23;
      if (ks < 2) {
        asm("v_cvt_pk_bf16_f32 %0, %1, %2" : "=v"(X01) : "v"(s0[a4 + 0]), "v"(s0[a4 + 1]));
        asm("v_cvt_pk_bf16_f32 %0, %1, %2" : "=v"(X23) : "v"(s0[a4 + 2]), "v"(s0[a4 + 3]));
        asm("v_cvt_pk_bf16_f32 %0, %1, %2" : "=v"(Y01) : "v"(s0[a4 + 4]), "v"(s0[a4 + 5]));
        asm("v_cvt_pk_bf16_f32 %0, %1, %2" : "=v"(Y23) : "v"(s0[a4 + 6]), "v"(s0[a4 + 7]));
      } else {
        asm("v_cvt_pk_bf16_f32 %0, %1, %2" : "=v"(X01) : "v"(s1[a4 + 0]), "v"(s1[a4 + 1]));
        asm("v_cvt_pk_bf16_f32 %0, %1, %2" : "=v"(X23) : "v"(s1[a4 + 2]), "v"(s1[a4 + 3]));
        asm("v_cvt_pk_bf16_f32 %0, %1, %2" : "=v"(Y01) : "v"(s1[a4 + 4]), "v"(s1[a4 + 5]));
        asm("v_cvt_pk_bf16_f32 %0, %1, %2" : "=v"(Y23) : "v"(s1[a4 + 6]), "v"(s1[a4 + 7]));
      }
      asm volatile("v_permlane32_swap_b32 %0, %1" : "+v"(X01), "+v"(Y01));
      asm volatile("v_permlane32_swap_b32 %0, %1" : "+v"(X23), "+v"(Y23));
      union { unsigned u[4]; bf16x8 v; } P;
      P.u[0] = X01; P.u[1] = X23; P.u[2] = Y01; P.u[3] = Y23;
      pa[ks] = P.v;
    }

    // O^acc += P @ V
#pragma unroll
    for (int ks = 0; ks < 4; ++ks) {
      acc0 = __builtin_amdgcn_mfma_f32_32x32x16_bf16(pa[ks], vb[0][ks], acc0, 0, 0, 0);
      acc1 = __builtin_amdgcn_mfma_f32_32x32x16_bf16(pa[ks], vb[1][ks], acc1, 0, 0, 0);
    }
  }

  // final l for this wave: tree over the 16 lsum regs + cross-half
#pragma unroll
  for (int off = 8; off > 0; off >>= 1)
#pragma unroll
    for (int rr = 0; rr < 8; ++rr)
      if (rr < off) lsum[rr] += lsum[rr + off];
  const float l_ = lsum[0] + __shfl_xor(lsum[0], 32);

  // ---- combine across the 4 kv-split waves, TWO passes (half the LDS) ----
  __shared__ float llds[4][32];
  __shared__ float obuf[4][64][17];  // stride 17: conflict-free, 17.4 KB

  if (hi2 == 0) llds[wave][lq] = l_;

  // pass 1: acc0
#pragma unroll
  for (int rr = 0; rr < 16; ++rr) obuf[wave][lane][rr] = acc0[rr];
  __syncthreads();

  const float Ltot = llds[0][lq] + llds[1][lq] + llds[2][lq] + llds[3][lq];
  const float linv = 1.0f / Ltot;

  float v0[4];
#pragma unroll
  for (int rr = 0; rr < 4; ++rr) {
    const int rq = wave * 4 + rr;
    v0[rr] = obuf[0][lane][rq] + obuf[1][lane][rq] + obuf[2][lane][rq] + obuf[3][lane][rq];
  }
  __syncthreads();

  // pass 2: acc1
#pragma unroll
  for (int rr = 0; rr < 16; ++rr) obuf[wave][lane][rr] = acc1[rr];
  __syncthreads();

#pragma unroll
  for (int rr = 0; rr < 4; ++rr) {
    const int rq = wave * 4 + rr;
    const float v1 = obuf[0][lane][rq] + obuf[1][lane][rq] + obuf[2][lane][rq] + obuf[3][lane][rq];
    const int row = (rq & 3) + 8 * (rq >> 2) + 4 * hi2;
    const float li = __shfl(linv, row);
    const size_t s = q0w + row;
    AO[s * D + h * DK + lq]      = f2bf(v0[rr] * li);
    AO[s * D + h * DK + 32 + lq] = f2bf(v1 * li);
  }
}

// ------- output projection (64x128 tile, dbuf single-barrier GEMM) ---------
// Re-tiled from 128x128 (grid 192 blocks = 0.75/CU, underfilled) to 64x128:
// grid (64,6) = 384 blocks = 1.5/CU, LDS 48KB dbuf -> 2-3 blocks/CU.
// 4 waves x (32 rows x 64 cols) quadrants — same per-wave shape as qkv.
__global__ __launch_bounds__(256) void oproj_kernel(
    const unsigned short* __restrict__ AO,
    const unsigned short* __restrict__ Wob,
    float* __restrict__ out) {
  __shared__ alignas(16) unsigned short At[2][64 * 64];
  __shared__ alignas(16) unsigned short Bt[2][128 * 64];

  const int t = threadIdx.x;
  const int lane = t & 63;
  const int lr = lane & 15;
  const int hi = lane >> 4;
  const int wave = t >> 6;              // 0..3
  const int wr = wave >> 1, wc = wave & 1;
  const int row0 = blockIdx.x * 64;
  const int n0 = blockIdx.y * 128;
  const int sx = lr & 7;

  f32x4 acc[2][4] = {};

  auto stage = [&](int buf, int k0) {
    // At: 512 chunks (2/thread), Bt: 1024 chunks (4/thread); ci lane-linear.
#pragma unroll
    for (int p = 0; p < 2; ++p) {
      const int ci = p * 256 + t;
      const int row = ci >> 3;
      const int c16 = ci & 7;
      const int csrc = (c16 ^ (row & 7)) * 8;
      __builtin_amdgcn_global_load_lds(
          (const __attribute__((address_space(1))) void*)(
              AO + (size_t)(row0 + row) * 768 + k0 + csrc),
          (__attribute__((address_space(3))) void*)(&At[buf][row * 64 + c16 * 8]),
          16, 0, 0);
    }
#pragma unroll
    for (int p = 0; p < 4; ++p) {
      const int ci = p * 256 + t;
      const int row = ci >> 3;
      const int c16 = ci & 7;
      const int csrc = (c16 ^ (row & 7)) * 8;
      __builtin_amdgcn_global_load_lds(
          (const __attribute__((address_space(1))) void*)(
              Wob + (size_t)(n0 + row) * 768 + k0 + csrc),
          (__attribute__((address_space(3))) void*)(&Bt[buf][row * 64 + c16 * 8]),
          16, 0, 0);
    }
  };

  stage(0, 0);
  __syncthreads();

#pragma unroll
  for (int ts = 0; ts < 12; ++ts) {
    const int cur = ts & 1;
    if (ts + 1 < 12) stage(cur ^ 1, (ts + 1) * 64);
#pragma unroll
    for (int kk = 0; kk < 2; ++kk) {
      const int csw = ((kk * 4 + hi) ^ sx) * 8;
      bf16x8 a[2], b[4];
#pragma unroll
      for (int rf = 0; rf < 2; ++rf)
        a[rf] = *reinterpret_cast<const bf16x8*>(
            &At[cur][(wr * 32 + rf * 16 + lr) * 64 + csw]);
#pragma unroll
      for (int nf = 0; nf < 4; ++nf)
        b[nf] = *reinterpret_cast<const bf16x8*>(
            &Bt[cur][(wc * 64 + nf * 16 + lr) * 64 + csw]);
#pragma unroll
      for (int rf = 0; rf < 2; ++rf)
#pragma unroll
        for (int nf = 0; nf < 4; ++nf)
          acc[rf][nf] = __builtin_amdgcn_mfma_f32_16x16x32_bf16(a[rf], b[nf], acc[rf][nf], 0, 0, 0);
    }
    __syncthreads();
  }

#pragma unroll
  for (int rf = 0; rf < 2; ++rf) {
    const int jrow = row0 + wr * 32 + rf * 16 + hi * 4;
#pragma unroll
    for (int nf = 0; nf < 4; ++nf) {
      const int cn = n0 + wc * 64 + nf * 16 + lr;
#pragma unroll
      for (int j = 0; j < 4; ++j)
        out[(size_t)(jrow + j) * D + cn] = acc[rf][nf][j];
    }
  }
}

extern "C" void kernel_launch(void* const* d_in, const int* in_sizes, int n_in,
                              void* d_out, int out_size, void* d_ws, size_t ws_size,
                              hipStream_t stream) {
  const float* x  = (const float*)d_in[0];
  const float* Wq = (const float*)d_in[1];
  const float* Wk = (const float*)d_in[2];
  const float* Wv = (const float*)d_in[3];
  const float* Wo = (const float*)d_in[4];
  float* out = (float*)d_out;

  char* ws = (char*)d_ws;
  unsigned short* xb  = (unsigned short*)(ws + 0);
  unsigned short* Wqb = (unsigned short*)(ws + 6291456);
  unsigned short* Wkb = (unsigned short*)(ws + 7471104);
  unsigned short* Wvb = (unsigned short*)(ws + 8650752);
  unsigned short* Wob = (unsigned short*)(ws + 9830400);
  unsigned short* Qh  = (unsigned short*)(ws + 11010048);  // [H][S][64] row-major
  unsigned short* Kf  = (unsigned short*)(ws + 17301504);  // frag-major K
  unsigned short* Vf  = (unsigned short*)(ws + 23592960);  // frag-major V
  unsigned short* AO  = (unsigned short*)(ws + 29884416);  // [S][D]
  // rope table overlaps the first 1 MB of the AO region: tab is fully
  // consumed by qkv_gemm_kernel before attn_kernel writes AO (stream order).
  float2* tab = (float2*)(ws + 29884416);

  // 1376256 cvt items + 131072 tab items = 1507328 -> 5888 blocks x 256
  cvt5_kernel<<<5888, 256, 0, stream>>>(x, Wq, Wk, Wv, Wo, xb, Wqb, Wkb, Wvb, Wob, tab);
  // Wqb|Wkb|Wvb are contiguous -> one stacked weight matrix [2304][768]
  qkv_gemm_kernel<<<dim3(32, 18), 512, 0, stream>>>(xb, Wqb, tab, Qh, Kf, Vf);
  // XCD-partitioned, balanced heavy-first classes (r14 structure)
  attn_kernel<<<dim3(8, 192), 256, 0, stream>>>(Qh, Kf, Vf, AO);
  oproj_kernel<<<dim3(64, 6), 256, 0, stream>>>(AO, Wob, out);
}